// Round 2
// baseline (16440.784 us; speedup 1.0000x reference)
//
#include <hip/hip_runtime.h>

#define SYNCH 32896
#define EPS 1e-5f

// ---------------- reduction helpers (256-thread blocks = 4 waves) -------------
__device__ __forceinline__ float wave_sum(float v) {
#pragma unroll
  for (int o = 32; o; o >>= 1) v += __shfl_xor(v, o, 64);
  return v;
}
__device__ __forceinline__ float wave_max(float v) {
#pragma unroll
  for (int o = 32; o; o >>= 1) v = fmaxf(v, __shfl_xor(v, o, 64));
  return v;
}
__device__ __forceinline__ float block_sum(float v, float* red, int t) {
  v = wave_sum(v);
  __syncthreads();
  if ((t & 63) == 0) red[t >> 6] = v;
  __syncthreads();
  return red[0] + red[1] + red[2] + red[3];
}
__device__ __forceinline__ float block_max(float v, float* red, int t) {
  v = wave_max(v);
  __syncthreads();
  if ((t & 63) == 0) red[t >> 6] = v;
  __syncthreads();
  return fmaxf(fmaxf(red[0], red[1]), fmaxf(red[2], red[3]));
}
__device__ __forceinline__ float sigm(float x) { return 1.f / (1.f + __expf(-x)); }

// ---------------- conv1 (3->256, 64x64, SAME 3x3) -----------------------------
__device__ __forceinline__ float conv1_at(const float* __restrict__ x,
                                          const float* __restrict__ w,
                                          int b, int o, int y, int xx) {
  float acc = 0.f;
#pragma unroll
  for (int c = 0; c < 3; ++c) {
    const float* xp = x + ((b * 3 + c) << 12);
    const float* wp = w + (o * 3 + c) * 9;
#pragma unroll
    for (int ky = 0; ky < 3; ++ky) {
      int iy = y + ky - 1;
      if ((unsigned)iy > 63u) continue;
#pragma unroll
      for (int kx = 0; kx < 3; ++kx) {
        int ix = xx + kx - 1;
        if ((unsigned)ix > 63u) continue;
        acc += xp[(iy << 6) + ix] * wp[ky * 3 + kx];
      }
    }
  }
  return acc;
}

__global__ __launch_bounds__(256) void conv1_stats_k(const float* __restrict__ x,
    const float* __restrict__ w, const float* __restrict__ bias, float* __restrict__ st) {
  int idx = blockIdx.x * 256 + threadIdx.x;
  int xx = idx & 63, yy = (idx >> 6) & 63, o = (idx >> 12) & 255, b = idx >> 20;
  float v = bias[o] + conv1_at(x, w, b, o, yy, xx);
  __shared__ float red[4];
  float s = block_sum(v, red, threadIdx.x);
  float s2 = block_sum(v * v, red, threadIdx.x);
  if (threadIdx.x == 0) { atomicAdd(&st[o], s); atomicAdd(&st[256 + o], s2); }
}

__global__ void bn_final_k(const float* st, float* m, float* inv, float n) {
  int o = threadIdx.x;  // 256
  float mu = st[o] / n;
  float var = st[256 + o] / n - mu * mu;
  m[o] = mu; inv[o] = rsqrtf(var + EPS);
}

__global__ __launch_bounds__(256) void conv1_pool_k(const float* __restrict__ x,
    const float* __restrict__ w, const float* __restrict__ bias,
    const float* __restrict__ m, const float* __restrict__ inv,
    const float* __restrict__ g, const float* __restrict__ bb,
    float* __restrict__ h1) {
  int idx = blockIdx.x * 256 + threadIdx.x;
  int xx = idx & 31, yy = (idx >> 5) & 31, o = (idx >> 10) & 255, b = idx >> 18;
  float mu = m[o], iv = inv[o], gg = g[o], be = bb[o], bi = bias[o];
  float best = -1e30f;
#pragma unroll
  for (int py = 0; py < 2; ++py)
#pragma unroll
    for (int px = 0; px < 2; ++px) {
      float v = bi + conv1_at(x, w, b, o, 2 * yy + py, 2 * xx + px);
      v = fmaxf(gg * (v - mu) * iv + be, 0.f);
      best = fmaxf(best, v);
    }
  h1[((b * 256 + o) * 32 + yy) * 32 + xx] = best;
}

// ---------------- conv2 (256->256, 32x32, SAME 3x3), LDS tiled ----------------
__global__ __launch_bounds__(256) void conv2_k(const float* __restrict__ h1,
    const float* __restrict__ w, const float* __restrict__ bias, float* __restrict__ y2) {
  __shared__ __align__(16) float tile[34 * 36];
  int b = blockIdx.x >> 4;
  int og = blockIdx.x & 15;
  int t = threadIdx.x;
  int o = og * 16 + (t >> 4);
  int l = t & 15;
  int x0 = (l & 3) * 8, y0 = (l >> 2) * 8;
  float acc[8][8];
#pragma unroll
  for (int i = 0; i < 8; ++i)
#pragma unroll
    for (int j = 0; j < 8; ++j) acc[i][j] = 0.f;
  for (int c = 0; c < 256; ++c) {
    __syncthreads();
    for (int i = t; i < 34 * 34; i += 256) {
      int r = i / 34, cc = i - r * 34;
      int iy = r - 1, ix = cc - 1;
      float v = 0.f;
      if ((unsigned)iy < 32u && (unsigned)ix < 32u) v = h1[((b * 256 + c) * 32 + iy) * 32 + ix];
      tile[r * 36 + cc] = v;
    }
    __syncthreads();
    const float* wp = w + (o * 256 + c) * 9;
    float w0 = wp[0], w1 = wp[1], w2 = wp[2], w3 = wp[3], w4 = wp[4],
          w5 = wp[5], w6 = wp[6], w7 = wp[7], w8 = wp[8];
#pragma unroll
    for (int r = 0; r < 10; ++r) {
      const float* trow = &tile[(y0 + r) * 36 + x0];
      float4 A = *(const float4*)trow;
      float4 Bq = *(const float4*)(trow + 4);
      float4 Cq = *(const float4*)(trow + 8);
      float v[12] = {A.x, A.y, A.z, A.w, Bq.x, Bq.y, Bq.z, Bq.w, Cq.x, Cq.y, Cq.z, Cq.w};
#pragma unroll
      for (int i = 0; i < 8; ++i) {
        int ky = r - i;
        if (ky < 0 || ky > 2) continue;
        float wk0 = (ky == 0) ? w0 : (ky == 1) ? w3 : w6;
        float wk1 = (ky == 0) ? w1 : (ky == 1) ? w4 : w7;
        float wk2 = (ky == 0) ? w2 : (ky == 1) ? w5 : w8;
#pragma unroll
        for (int j = 0; j < 8; ++j)
          acc[i][j] += v[j] * wk0 + v[j + 1] * wk1 + v[j + 2] * wk2;
      }
    }
  }
  float bo = bias[o];
#pragma unroll
  for (int i = 0; i < 8; ++i)
#pragma unroll
    for (int j = 0; j < 8; ++j)
      y2[((b * 256 + o) * 32 + y0 + i) * 32 + x0 + j] = acc[i][j] + bo;
}

__global__ __launch_bounds__(256) void bn2_stats_k(const float* __restrict__ y2,
    float* __restrict__ m2, float* __restrict__ i2) {
  int o = blockIdx.x, t = threadIdx.x;
  float s = 0.f, s2 = 0.f;
  for (int i = t; i < 65536; i += 256) {
    int b = i >> 10, sp = i & 1023;
    float v = y2[((b << 8) + o) * 1024 + sp];
    s += v; s2 += v * v;
  }
  __shared__ float red[4];
  float S = block_sum(s, red, t);
  float S2 = block_sum(s2, red, t);
  if (t == 0) {
    float mu = S / 65536.f;
    m2[o] = mu;
    i2[o] = rsqrtf(S2 / 65536.f - mu * mu + EPS);
  }
}

__global__ __launch_bounds__(256) void pool2_k(const float* __restrict__ y2,
    const float* __restrict__ m2, const float* __restrict__ i2,
    const float* __restrict__ g, const float* __restrict__ bb, float* __restrict__ feat) {
  int idx = blockIdx.x * 256 + threadIdx.x;
  int d = idx & 255, s = (idx >> 8) & 255, b = idx >> 16;
  int yy = s >> 4, xx = s & 15;
  const float* base = y2 + ((size_t)(b * 256 + d) << 10);
  float mu = m2[d], iv = i2[d], gg = g[d], be = bb[d];
  float best = -1e30f;
#pragma unroll
  for (int py = 0; py < 2; ++py)
#pragma unroll
    for (int px = 0; px < 2; ++px) {
      float v = base[(2 * yy + py) * 32 + 2 * xx + px];
      v = fmaxf(gg * (v - mu) * iv + be, 0.f);
      best = fmaxf(best, v);
    }
  feat[(b * 256 + s) * 256 + d] = best;
}

// ---------------- generic tiled GEMM: C = [A|A2] @ W (+bias), 64x64 tile ------
// mode 0: direct write (+bias if z==0). mode 2: z-split partials, no bias.
__global__ __launch_bounds__(256) void gemm4x4_k(const float* __restrict__ A, int lda,
    const float* __restrict__ A2, int lda2, int K1,
    const float* __restrict__ W, const float* __restrict__ bias,
    float* __restrict__ C, int M, int N, int K, int kchunk, int mode) {
  __shared__ __align__(16) float As[16][68];
  __shared__ __align__(16) float Ws[16][68];
  int tx = threadIdx.x, ty = threadIdx.y;
  int tid = ty * 16 + tx;
  int n0 = blockIdx.x * 64, m0 = blockIdx.y * 64;
  int k_lo = blockIdx.z * kchunk;
  int k_hi = min(K, k_lo + kchunk);
  float acc[4][4];
#pragma unroll
  for (int i = 0; i < 4; ++i)
#pragma unroll
    for (int j = 0; j < 4; ++j) acc[i][j] = 0.f;
  for (int k0 = k_lo; k0 < k_hi; k0 += 16) {
    __syncthreads();
#pragma unroll
    for (int q = 0; q < 4; ++q) {
      int r = (tid >> 4) + q * 16, c = tid & 15;
      int mm = m0 + r, kk = k0 + c;
      float a = 0.f;
      if (mm < M && kk < k_hi) a = (kk < K1) ? A[(size_t)mm * lda + kk] : A2[(size_t)mm * lda2 + kk - K1];
      As[c][r] = a;
    }
#pragma unroll
    for (int q = 0; q < 4; ++q) {
      int kk = (tid >> 6) + q * 4, nn = tid & 63;
      int kg = k0 + kk, n = n0 + nn;
      Ws[kk][nn] = (kg < k_hi && n < N) ? W[(size_t)kg * N + n] : 0.f;
    }
    __syncthreads();
#pragma unroll
    for (int kk = 0; kk < 16; ++kk) {
      float4 av = *(const float4*)&As[kk][ty * 4];
      float4 wv = *(const float4*)&Ws[kk][tx * 4];
      float av4[4] = {av.x, av.y, av.z, av.w};
      float wv4[4] = {wv.x, wv.y, wv.z, wv.w};
#pragma unroll
      for (int i = 0; i < 4; ++i)
#pragma unroll
        for (int j = 0; j < 4; ++j) acc[i][j] += av4[i] * wv4[j];
    }
  }
#pragma unroll
  for (int i = 0; i < 4; ++i) {
    int mm = m0 + ty * 4 + i;
    if (mm >= M) continue;
#pragma unroll
    for (int j = 0; j < 4; ++j) {
      int n = n0 + tx * 4 + j;
      if (n >= N) continue;
      float v = acc[i][j];
      if (mode == 2) {
        C[((size_t)blockIdx.z * M + mm) * N + n] = v;
      } else {
        if (bias && blockIdx.z == 0) v += bias[n];
        C[(size_t)mm * N + n] = v;
      }
    }
  }
}

// ---------------- LayerNorm over 256-wide rows (in place) ---------------------
__global__ __launch_bounds__(256) void ln256_k(float* __restrict__ x,
    const float* __restrict__ g, const float* __restrict__ b) {
  int row = blockIdx.x, t = threadIdx.x;
  float v = x[row * 256 + t];
  __shared__ float red[4];
  float mu = block_sum(v, red, t) * (1.f / 256.f);
  float d = v - mu;
  float var = block_sum(d * d, red, t) * (1.f / 256.f);
  float rs = rsqrtf(var + EPS);
  x[row * 256 + t] = g[t] * d * rs + b[t];
}

// ---------------- skinny GEMM: part[kc] = A(64,K)-chunk @ W-chunk -------------
// A rows are wave-uniform -> scalar loads; k-tiled by 8 for s_load_dwordx8.
__global__ __launch_bounds__(256) void skinny_k(const float* __restrict__ A,
    const float* __restrict__ W, float* __restrict__ part, int K, int N, int kchunk) {
  int n = blockIdx.x * 256 + threadIdx.x;
  int nc = min(n, N - 1);
  int kc = blockIdx.y;
  int k_lo = kc * kchunk, k_hi = min(K, k_lo + kchunk);
  float acc[64];
#pragma unroll
  for (int b = 0; b < 64; ++b) acc[b] = 0.f;
  int k = k_lo;
  for (; k + 8 <= k_hi; k += 8) {
    float w[8];
#pragma unroll
    for (int j = 0; j < 8; ++j) w[j] = W[(size_t)(k + j) * N + nc];
#pragma unroll
    for (int b = 0; b < 64; ++b) {
      const float* __restrict__ ap = A + b * K + k;
#pragma unroll
      for (int j = 0; j < 8; ++j) acc[b] = fmaf(ap[j], w[j], acc[b]);
    }
  }
  for (; k < k_hi; ++k) {
    float w0 = W[(size_t)k * N + nc];
#pragma unroll
    for (int b = 0; b < 64; ++b) acc[b] = fmaf(A[b * K + k], w0, acc[b]);
  }
  if (n < N) {
#pragma unroll
    for (int b = 0; b < 64; ++b) part[(size_t)(kc * 64 + b) * N + n] = acc[b];
  }
}

// ---------------- attention: one block per (b,h); folds q split-K reduce ------
__global__ __launch_bounds__(256) void attn_k(const float* __restrict__ part_q,
    const float* __restrict__ qbq, const float* __restrict__ kh,
    const float* __restrict__ vh, float* __restrict__ out, int nkc) {
  int b = blockIdx.x >> 3, h = blockIdx.x & 7;
  int t = threadIdx.x;
  __shared__ float q8[256];
  __shared__ float qs[32];
  __shared__ float wgt[256];
  __shared__ float pv[256];
  __shared__ float red[4];
  {
    int d = t & 31, g = t >> 5;
    float s = 0.f;
    for (int kc = g; kc < nkc; kc += 8)
      s += part_q[(size_t)(kc * 64 + b) * 256 + h * 32 + d];
    q8[t] = s;
  }
  __syncthreads();
  if (t < 32) {
    float s = qbq[h * 32 + t];
#pragma unroll
    for (int g = 0; g < 8; ++g) s += q8[g * 32 + t];
    qs[t] = s;
  }
  __syncthreads();
  const float4* kp = (const float4*)(kh + ((size_t)((b * 256 + t) * 8 + h)) * 32);
  float sc = 0.f;
#pragma unroll
  for (int q = 0; q < 8; ++q) {
    float4 k4 = kp[q];
    sc += k4.x * qs[4 * q] + k4.y * qs[4 * q + 1] + k4.z * qs[4 * q + 2] + k4.w * qs[4 * q + 3];
  }
  sc *= 0.17677669529663687f;  // 1/sqrt(32)
  float M = block_max(sc, red, t);
  float e = __expf(sc - M);
  float S = block_sum(e, red, t);
  wgt[t] = e / S;
  __syncthreads();
  int d = t & 31, grp = t >> 5;
  float a = 0.f;
  for (int s = grp; s < 256; s += 8)
    a += wgt[s] * vh[((size_t)((b * 256 + s) * 8 + h)) * 32 + d];
  pv[t] = a;
  __syncthreads();
  if (t < 32) {
    float s = 0.f;
#pragma unroll
    for (int g2 = 0; g2 < 8; ++g2) s += pv[g2 * 32 + t];
    out[b * 256 + h * 32 + t] = s;
  }
}

// ---------------- reduce syn partials + bias + GLU + LN -> trace ring slot ----
__global__ __launch_bounds__(256) void gluln_k(const float* __restrict__ part2,
    const float* __restrict__ biasyn,
    const float* __restrict__ g, const float* __restrict__ bb,
    float* __restrict__ trace, int slot) {
  int b = blockIdx.x, t = threadIdx.x;
  float v[4];
  float s = 0.f;
#pragma unroll
  for (int i = 0; i < 4; ++i) {
    int d = i * 256 + t;
    float a = biasyn[d];
    float gg = biasyn[1024 + d];
#pragma unroll
    for (int z = 0; z < 8; ++z) {
      const float* p = part2 + (size_t)(z * 64 + b) * 2048;
      a += p[d];
      gg += p[1024 + d];
    }
    v[i] = a * sigm(gg);
    s += v[i];
  }
  __shared__ float red[4];
  float mu = block_sum(s, red, t) * (1.f / 1024.f);
  float s2 = 0.f;
#pragma unroll
  for (int i = 0; i < 4; ++i) { float d0 = v[i] - mu; s2 += d0 * d0; }
  float var = block_sum(s2, red, t) * (1.f / 1024.f);
  float rs = rsqrtf(var + EPS);
  float* tr = trace + (b * 25 + slot) * 1024;
#pragma unroll
  for (int i = 0; i < 4; ++i) {
    int d = i * 256 + t;
    tr[d] = g[d] * (v[i] - mu) * rs + bb[d];
  }
}

// ---------------- tp1 einsum + GLU: hmid[b,h,d] -------------------------------
#define FMA4(dst, sv, wv) dst.x += sv.x*wv.x; dst.y += sv.y*wv.y; dst.z += sv.z*wv.z; dst.w += sv.w*wv.w;
__global__ __launch_bounds__(256) void tp1_k(const float* __restrict__ trace,
    const float* __restrict__ w1, const float* __restrict__ b1,
    float* __restrict__ hmid, int toff) {
  int gx = blockIdx.x * 256 + threadIdx.x;  // 65536
  int d4 = gx & 255;
  int hg = (gx >> 8) & 7;
  int bp = gx >> 11;
  int b0 = bp * 2;
  int h0 = hg * 8;
  float4 acc[2][2][8];
#pragma unroll
  for (int a = 0; a < 2; ++a)
#pragma unroll
    for (int c = 0; c < 2; ++c)
#pragma unroll
      for (int u = 0; u < 8; ++u) acc[a][c][u] = make_float4(0.f, 0.f, 0.f, 0.f);
  for (int m = 0; m < 25; ++m) {
    int pm = toff + m; if (pm >= 25) pm -= 25;
    float4 t0 = *(const float4*)&trace[((b0) * 25 + pm) * 1024 + d4 * 4];
    float4 t1 = *(const float4*)&trace[((b0 + 1) * 25 + pm) * 1024 + d4 * 4];
    const float* wb = w1 + m * 131072 + d4 * 4;
#pragma unroll
    for (int u = 0; u < 8; ++u) {
      float4 wa = *(const float4*)&wb[(h0 + u) * 1024];
      float4 wg = *(const float4*)&wb[(64 + h0 + u) * 1024];
      FMA4(acc[0][0][u], t0, wa); FMA4(acc[0][1][u], t0, wg);
      FMA4(acc[1][0][u], t1, wa); FMA4(acc[1][1][u], t1, wg);
    }
  }
  int dbase = d4 * 4;
#pragma unroll
  for (int u = 0; u < 8; ++u) {
    int h = h0 + u;
#pragma unroll
    for (int bb2 = 0; bb2 < 2; ++bb2) {
      float4 av = acc[bb2][0][u], gv = acc[bb2][1][u];
      av.x += b1[(dbase + 0) * 128 + h];      av.y += b1[(dbase + 1) * 128 + h];
      av.z += b1[(dbase + 2) * 128 + h];      av.w += b1[(dbase + 3) * 128 + h];
      gv.x += b1[(dbase + 0) * 128 + 64 + h]; gv.y += b1[(dbase + 1) * 128 + 64 + h];
      gv.z += b1[(dbase + 2) * 128 + 64 + h]; gv.w += b1[(dbase + 3) * 128 + 64 + h];
      float4 hm;
      hm.x = av.x * sigm(gv.x); hm.y = av.y * sigm(gv.y);
      hm.z = av.z * sigm(gv.z); hm.w = av.w * sigm(gv.w);
      *(float4*)&hmid[((b0 + bb2) * 64 + h) * 1024 + dbase] = hm;
    }
  }
}

__global__ __launch_bounds__(256) void tp2_k(const float* __restrict__ hmid,
    const float* __restrict__ w2, const float* __restrict__ b2, float* __restrict__ act) {
  int gx = blockIdx.x * 256 + threadIdx.x;  // 65536
  int d = gx & 1023, b = gx >> 10;
  float a = b2[d * 2], gg = b2[d * 2 + 1];
  for (int h = 0; h < 64; ++h) {
    float hm = hmid[(b * 64 + h) * 1024 + d];
    a += hm * w2[(h * 2) * 1024 + d];
    gg += hm * w2[(h * 2 + 1) * 1024 + d];
  }
  act[gx] = a * sigm(gg);
}

// ---------------- synchronisation, (b,p) layout, closed-form beta -------------
__global__ __launch_bounds__(256) void synch_k(const float* __restrict__ act,
    const int* __restrict__ I, const int* __restrict__ J,
    const float* __restrict__ decay, int off, int n, int has_init,
    float* __restrict__ al, float* __restrict__ so) {
  int p = blockIdx.x * 256 + threadIdx.x;
  if (p >= SYNCH) return;
  int b = blockIdx.y;
  const float* arow = act + b * 1024 + off;
  float pp = arow[I[p]] * arow[J[p]];
  float d = decay[p];
  float r = __expf(-d);
  size_t idx = (size_t)b * SYNCH + p;
  float a = r * al[idx] + pp;
  al[idx] = a;
  float em1d = expm1f(-d);                  // r - 1  (negative)
  float em1nd = expm1f(-(float)n * d);      // r^n - 1
  float beta = (em1d == 0.f) ? (float)n : em1nd / em1d;  // (1-r^n)/(1-r)
  if (has_init) beta += em1nd + 1.f;        // + r^n
  so[idx] = a * rsqrtf(beta);
}

// ---------------- pred split-K reduce + logits + entropy certainty ------------
__global__ __launch_bounds__(256) void predent_k(const float* __restrict__ part,
    const float* __restrict__ bias, float* __restrict__ dout, int nkc, int t) {
  int b = blockIdx.x, tid = threadIdx.x;
  __shared__ float sp[1000];
  __shared__ float red[4];
  float mx = -1e30f;
  for (int i = tid; i < 1000; i += 256) {
    float s = bias[i];
    for (int kc = 0; kc < nkc; ++kc) s += part[(size_t)(kc * 64 + b) * 1000 + i];
    sp[i] = s;
    mx = fmaxf(mx, s);
  }
  float M = block_max(mx, red, tid);
  float se = 0.f;
  for (int i = tid; i < 1000; i += 256) se += __expf(sp[i] - M);
  float S = block_sum(se, red, tid);
  float lse = M + __logf(S);
  float acc = 0.f;
  for (int i = tid; i < 1000; i += 256) {
    float lp = sp[i] - lse;
    acc += __expf(lp) * lp;
    dout[b * 16000 + i * 16 + t] = sp[i];
  }
  float E = block_sum(acc, red, tid);
  if (tid == 0) {
    float ne = -E * (1.f / 6.907755278982137f);  // / ln(1000)
    dout[1024000 + b * 32 + t] = ne;
    dout[1024000 + b * 32 + 16 + t] = 1.f - ne;
  }
}

// ---------------- small setup / fold kernels ----------------------------------
__global__ void triu_k(int* __restrict__ I, int* __restrict__ J) {
  int p = blockIdx.x * 256 + threadIdx.x;
  if (p >= SYNCH) return;
  float pf = (float)p;
  int i = (int)floorf((513.f - sqrtf(513.f * 513.f - 8.f * pf)) * 0.5f);
  i = max(0, min(255, i));
  while (i > 0 && i * (513 - i) / 2 > p) --i;
  while (i < 255 && (i + 1) * (513 - (i + 1)) / 2 <= p) ++i;
  I[p] = i;
  J[p] = i + (p - i * (513 - i) / 2);
}

__global__ void initact_k(const float* sa, float* act) {
  int gx = blockIdx.x * 256 + threadIdx.x;  // 65536
  act[gx] = sa[gx & 1023];
}

__global__ void inittrace_k(const float* st, float* trace) {
  int r = blockIdx.x * 256 + threadIdx.x;  // < 25600
  int b = blockIdx.y;
  int m = r >> 10, d = r & 1023;
  trace[(b * 25 + m) * 1024 + d] = st[d * 25 + m];
}

__global__ void initsynch_k(const int* __restrict__ I, const int* __restrict__ J,
    const float* __restrict__ sa, float* aa, float* ao) {
  int p = blockIdx.x * 256 + threadIdx.x;
  if (p >= SYNCH) return;
  int b = blockIdx.y;
  size_t idx = (size_t)b * SYNCH + p;
  aa[idx] = 0.f;
  ao[idx] = sa[I[p]] * sa[J[p]];
}

__global__ void soout_k(const float* __restrict__ so, float* __restrict__ dout) {
  int p = blockIdx.x * 256 + threadIdx.x;
  if (p >= SYNCH) return;
  int b = blockIdx.y;
  dout[1026048 + (size_t)b * SYNCH + p] = so[(size_t)b * SYNCH + p];
}

// out[n] = bias2[n] + sum_k v[k] * W[k*N+n]
__global__ void vecbias_k(const float* __restrict__ v, const float* __restrict__ W,
    const float* __restrict__ bias, float* __restrict__ out, int K, int N) {
  int n = blockIdx.x * 256 + threadIdx.x;
  if (n >= N) return;
  float s = bias[n];
  for (int k = 0; k < K; ++k) s += v[k] * W[(size_t)k * N + n];
  out[n] = s;
}

__global__ void copy_k(const float* __restrict__ src, float* __restrict__ dst, int count) {
  int i = blockIdx.x * 256 + threadIdx.x;
  if (i < count) dst[i] = src[i];
}

// ------------------------------------------------------------------------------
extern "C" void kernel_launch(void* const* d_in, const int* in_sizes, int n_in,
                              void* d_out, int out_size, void* d_ws, size_t ws_size,
                              hipStream_t stream) {
  (void)in_sizes; (void)n_in; (void)out_size; (void)ws_size;
  const float* x      = (const float*)d_in[0];
  const float* c1w    = (const float*)d_in[1];
  const float* c1b    = (const float*)d_in[2];
  const float* bn1g   = (const float*)d_in[3];
  const float* bn1b   = (const float*)d_in[4];
  const float* c2w    = (const float*)d_in[5];
  const float* c2b    = (const float*)d_in[6];
  const float* bn2g   = (const float*)d_in[7];
  const float* bn2b   = (const float*)d_in[8];
  const float* kvw    = (const float*)d_in[9];
  const float* kvb    = (const float*)d_in[10];
  const float* lnkvg  = (const float*)d_in[11];
  const float* lnkvb  = (const float*)d_in[12];
  const float* qw     = (const float*)d_in[13];
  const float* qb     = (const float*)d_in[14];
  const float* wq     = (const float*)d_in[15];
  const float* bq     = (const float*)d_in[16];
  const float* wk     = (const float*)d_in[17];
  const float* bk     = (const float*)d_in[18];
  const float* wv     = (const float*)d_in[19];
  const float* bv     = (const float*)d_in[20];
  const float* wo     = (const float*)d_in[21];
  const float* bop    = (const float*)d_in[22];
  const float* synw   = (const float*)d_in[23];
  const float* synb   = (const float*)d_in[24];
  const float* lnsg   = (const float*)d_in[25];
  const float* lnsb   = (const float*)d_in[26];
  const float* t1w    = (const float*)d_in[27];
  const float* t1b    = (const float*)d_in[28];
  const float* t2w    = (const float*)d_in[29];
  const float* t2b    = (const float*)d_in[30];
  const float* outw   = (const float*)d_in[31];
  const float* outb   = (const float*)d_in[32];
  const float* sact   = (const float*)d_in[33];
  const float* strace = (const float*)d_in[34];
  const float* dca    = (const float*)d_in[35];
  const float* dco    = (const float*)d_in[36];
  float* out = (float*)d_out;

  float* W = (float*)d_ws;
  size_t off = 0;
  auto alloc = [&](size_t n) { float* p = W + off; off += (n + 63) & ~(size_t)63; return p; };
  float* h1     = alloc(16777216);   // frontend only; reused for kv/kh/vh
  float* y2     = alloc(16777216);   // frontend only; reused for qwq/wcat
  float* feat   = alloc(4194304);
  float* st     = alloc(512);
  float* m1     = alloc(256); float* i1 = alloc(256);
  float* m2     = alloc(256); float* i2 = alloc(256);
  int*   tI     = (int*)alloc(32896);
  int*   tJ     = (int*)alloc(32896);
  float* aa     = alloc(2105344);
  float* ao     = alloc(2105344);
  float* sa     = alloc(2105344);
  float* so     = alloc(2105344);
  float* act    = alloc(65536);
  float* trace  = alloc(1638400);
  float* part_q = alloc(2097152);    // 128*64*256
  float* part2  = alloc(1048576);    // 8*64*2048
  float* hmid   = alloc(4194304);
  float* part   = alloc(8192000);    // 128*64*1000
  float* ath    = alloc(16384);
  float* qbq    = alloc(256);
  float* biasyn = alloc(2048);

  // aliases into dead frontend buffers
  float* kv   = h1;                  // 4194304
  float* kh   = h1 + 4194304;        // 4194304
  float* vh   = h1 + 8388608;        // 4194304
  float* qwq  = y2;                  // 32896*256 = 8421376
  float* wcat = y2 + 8421376;        // 1280*2048 = 2621440

  dim3 thr(16, 16);

  // -------- frontend --------
  hipMemsetAsync(st, 0, 512 * sizeof(float), stream);
  conv1_stats_k<<<262144, 256, 0, stream>>>(x, c1w, c1b, st);
  bn_final_k<<<1, 256, 0, stream>>>(st, m1, i1, 262144.f);
  conv1_pool_k<<<65536, 256, 0, stream>>>(x, c1w, c1b, m1, i1, bn1g, bn1b, h1);
  conv2_k<<<1024, 256, 0, stream>>>(h1, c2w, c2b, y2);
  bn2_stats_k<<<256, 256, 0, stream>>>(y2, m2, i2);
  pool2_k<<<16384, 256, 0, stream>>>(y2, m2, i2, bn2g, bn2b, feat);
  // h1, y2 now dead -> aliases become live
  gemm4x4_k<<<dim3(4, 256, 1), thr, 0, stream>>>(feat, 256, feat, 256, 256, kvw, kvb, kv, 16384, 256, 256, 256, 0);
  ln256_k<<<16384, 256, 0, stream>>>(kv, lnkvg, lnkvb);
  gemm4x4_k<<<dim3(4, 256, 1), thr, 0, stream>>>(kv, 256, kv, 256, 256, wk, bk, kh, 16384, 256, 256, 256, 0);
  gemm4x4_k<<<dim3(4, 256, 1), thr, 0, stream>>>(kv, 256, kv, 256, 256, wv, bv, vh, 16384, 256, 256, 256, 0);
  // folded weights
  gemm4x4_k<<<dim3(4, 514, 1), thr, 0, stream>>>(qw, 256, qw, 256, 256, wq, nullptr, qwq, 32896, 256, 256, 256, 0);
  gemm4x4_k<<<dim3(32, 4, 1), thr, 0, stream>>>(wo, 256, wo, 256, 256, synw, nullptr, wcat, 256, 2048, 256, 256, 0);
  copy_k<<<8192, 256, 0, stream>>>(synw + 524288, wcat + 524288, 2097152);
  vecbias_k<<<1, 256, 0, stream>>>(qb, wq, bq, qbq, 256, 256);
  vecbias_k<<<8, 256, 0, stream>>>(bop, synw, synb, biasyn, 256, 2048);

  // -------- recurrent-state setup --------
  triu_k<<<129, 256, 0, stream>>>(tI, tJ);
  initact_k<<<256, 256, 0, stream>>>(sact, act);
  inittrace_k<<<dim3(100, 64), 256, 0, stream>>>(strace, trace);
  initsynch_k<<<dim3(129, 64), 256, 0, stream>>>(tI, tJ, sact, aa, ao);

  // -------- 16 thought iterations --------
  for (int t = 0; t < 16; ++t) {
    synch_k<<<dim3(129, 64), 256, 0, stream>>>(act, tI, tJ, dca, 768, t + 1, 0, aa, sa);
    skinny_k<<<dim3(1, 128), 256, 0, stream>>>(sa, qwq, part_q, 32896, 256, 257);
    attn_k<<<512, 256, 0, stream>>>(part_q, qbq, kh, vh, ath, 128);
    gemm4x4_k<<<dim3(32, 1, 8), thr, 0, stream>>>(ath, 256, act, 1024, 256, wcat, nullptr, part2, 64, 2048, 1280, 160, 2);
    gluln_k<<<64, 256, 0, stream>>>(part2, biasyn, lnsg, lnsb, trace, t);
    tp1_k<<<256, 256, 0, stream>>>(trace, t1w, t1b, hmid, t + 1);
    tp2_k<<<256, 256, 0, stream>>>(hmid, t2w, t2b, act);
    synch_k<<<dim3(129, 64), 256, 0, stream>>>(act, tI, tJ, dco, 0, t + 1, 1, ao, so);
    skinny_k<<<dim3(4, 128), 256, 0, stream>>>(so, outw, part, 32896, 1000, 257);
    predent_k<<<64, 256, 0, stream>>>(part, outb, out, 128, t);
  }
  soout_k<<<dim3(129, 64), 256, 0, stream>>>(so, out);
}

// Round 3
// 12175.622 us; speedup vs baseline: 1.3503x; 1.3503x over previous
//
#include <hip/hip_runtime.h>

#define SYNCH 32896
#define EPS 1e-5f

// ---------------- reduction helpers (256-thread blocks = 4 waves) -------------
__device__ __forceinline__ float wave_sum(float v) {
#pragma unroll
  for (int o = 32; o; o >>= 1) v += __shfl_xor(v, o, 64);
  return v;
}
__device__ __forceinline__ float wave_max(float v) {
#pragma unroll
  for (int o = 32; o; o >>= 1) v = fmaxf(v, __shfl_xor(v, o, 64));
  return v;
}
__device__ __forceinline__ float block_sum(float v, float* red, int t) {
  v = wave_sum(v);
  __syncthreads();
  if ((t & 63) == 0) red[t >> 6] = v;
  __syncthreads();
  return red[0] + red[1] + red[2] + red[3];
}
__device__ __forceinline__ float block_max(float v, float* red, int t) {
  v = wave_max(v);
  __syncthreads();
  if ((t & 63) == 0) red[t >> 6] = v;
  __syncthreads();
  return fmaxf(fmaxf(red[0], red[1]), fmaxf(red[2], red[3]));
}
__device__ __forceinline__ float sigm(float x) { return 1.f / (1.f + __expf(-x)); }

// ---------------- conv1 (3->256): register-blocked 2x2 quads ------------------
// Block = one (b,o) plane. Each thread processes 4 quads of 2x2 conv outputs,
// loading a 4x4x3 input patch into registers per quad (12 loads per conv).
__device__ __forceinline__ void load_patch(const float* __restrict__ x, int b,
                                           int r0, int c0, float p[3][4][4]) {
#pragma unroll
  for (int c = 0; c < 3; ++c) {
    const float* xp = x + ((b * 3 + c) << 12);
#pragma unroll
    for (int dy = 0; dy < 4; ++dy) {
      int iy = r0 + dy;
      bool yok = (unsigned)iy < 64u;
#pragma unroll
      for (int dx = 0; dx < 4; ++dx) {
        int ix = c0 + dx;
        p[c][dy][dx] = (yok && (unsigned)ix < 64u) ? xp[(iy << 6) + ix] : 0.f;
      }
    }
  }
}

__device__ __forceinline__ float conv_at_patch(const float p[3][4][4],
                                               const float wr[3][9], int dy, int dx) {
  float v = 0.f;
#pragma unroll
  for (int c = 0; c < 3; ++c)
#pragma unroll
    for (int ky = 0; ky < 3; ++ky)
#pragma unroll
      for (int kx = 0; kx < 3; ++kx)
        v = fmaf(p[c][dy + ky][dx + kx], wr[c][ky * 3 + kx], v);
  return v;
}

__global__ __launch_bounds__(256) void conv1_stats_k(const float* __restrict__ x,
    const float* __restrict__ w, const float* __restrict__ bias,
    float* __restrict__ s1, float* __restrict__ s2) {
  int b = blockIdx.x >> 8, o = blockIdx.x & 255, t = threadIdx.x;
  float wr[3][9];
#pragma unroll
  for (int c = 0; c < 3; ++c)
#pragma unroll
    for (int k = 0; k < 9; ++k) wr[c][k] = w[(o * 3 + c) * 9 + k];
  float bi = bias[o];
  float s = 0.f, ss = 0.f;
#pragma unroll
  for (int q = 0; q < 4; ++q) {
    int qid = t + 256 * q;        // 0..1023 over 32x32 quad grid
    int qy = qid >> 5, qx = qid & 31;
    float p[3][4][4];
    load_patch(x, b, 2 * qy - 1, 2 * qx - 1, p);
#pragma unroll
    for (int dy = 0; dy < 2; ++dy)
#pragma unroll
      for (int dx = 0; dx < 2; ++dx) {
        float v = bi + conv_at_patch(p, wr, dy, dx);
        s += v; ss += v * v;
      }
  }
  __shared__ float red[4];
  float S = block_sum(s, red, t);
  float SS = block_sum(ss, red, t);
  if (t == 0) { s1[blockIdx.x] = S; s2[blockIdx.x] = SS; }
}

__global__ void bn_final_k(const float* __restrict__ s1, const float* __restrict__ s2,
                           float* m, float* inv, float n) {
  int o = threadIdx.x;  // 256
  float s = 0.f, ss = 0.f;
  for (int b = 0; b < 64; ++b) { s += s1[b * 256 + o]; ss += s2[b * 256 + o]; }
  float mu = s / n;
  float var = ss / n - mu * mu;
  m[o] = mu; inv[o] = rsqrtf(var + EPS);
}

__global__ __launch_bounds__(256) void conv1_pool_k(const float* __restrict__ x,
    const float* __restrict__ w, const float* __restrict__ bias,
    const float* __restrict__ m, const float* __restrict__ inv,
    const float* __restrict__ g, const float* __restrict__ bb,
    float* __restrict__ h1) {
  int b = blockIdx.x >> 8, o = blockIdx.x & 255, t = threadIdx.x;
  float wr[3][9];
#pragma unroll
  for (int c = 0; c < 3; ++c)
#pragma unroll
    for (int k = 0; k < 9; ++k) wr[c][k] = w[(o * 3 + c) * 9 + k];
  float bi = bias[o];
  float mu = m[o], iv = inv[o], gg = g[o], be = bb[o];
#pragma unroll
  for (int q = 0; q < 4; ++q) {
    int pid = t + 256 * q;        // pooled output id, 32x32
    int py = pid >> 5, px = pid & 31;
    float p[3][4][4];
    load_patch(x, b, 2 * py - 1, 2 * px - 1, p);
    float best = -1e30f;
#pragma unroll
    for (int dy = 0; dy < 2; ++dy)
#pragma unroll
      for (int dx = 0; dx < 2; ++dx) {
        float v = bi + conv_at_patch(p, wr, dy, dx);
        v = fmaxf(gg * (v - mu) * iv + be, 0.f);
        best = fmaxf(best, v);
      }
    h1[((b * 256 + o) * 32 + py) * 32 + px] = best;
  }
}

// ---------------- conv2 (256->256, 32x32, SAME 3x3), LDS tiled ----------------
// Patch per thread: 4 wide x 16 tall -> x0 = 4*(l&7) spans 8 bank groups,
// y-stride 576 words == 0 mod 32 -> exactly 2 lanes/bank (free).
__global__ __launch_bounds__(256) void conv2_k(const float* __restrict__ h1,
    const float* __restrict__ w, const float* __restrict__ bias, float* __restrict__ y2) {
  __shared__ __align__(16) float tile[34 * 36];
  int b = blockIdx.x >> 4;
  int og = blockIdx.x & 15;
  int t = threadIdx.x;
  int o = og * 16 + (t >> 4);
  int l = t & 15;
  int x0 = (l & 7) * 4;   // 0..28
  int y0 = (l >> 3) * 16; // 0,16
  float acc[16][4];
#pragma unroll
  for (int i = 0; i < 16; ++i)
#pragma unroll
    for (int j = 0; j < 4; ++j) acc[i][j] = 0.f;
  for (int c = 0; c < 256; ++c) {
    __syncthreads();
    for (int i = t; i < 34 * 34; i += 256) {
      int r = i / 34, cc = i - r * 34;
      int iy = r - 1, ix = cc - 1;
      float v = 0.f;
      if ((unsigned)iy < 32u && (unsigned)ix < 32u) v = h1[((b * 256 + c) * 32 + iy) * 32 + ix];
      tile[r * 36 + cc] = v;
    }
    __syncthreads();
    const float* wp = w + (o * 256 + c) * 9;
    float w0 = wp[0], w1 = wp[1], w2 = wp[2], w3 = wp[3], w4 = wp[4],
          w5 = wp[5], w6 = wp[6], w7 = wp[7], w8 = wp[8];
    float c0[6], c1[6], c2[6];
    {
      const float* p0 = &tile[(y0 + 0) * 36 + x0];
      float4 v0 = *(const float4*)p0;
      c0[0] = v0.x; c0[1] = v0.y; c0[2] = v0.z; c0[3] = v0.w; c0[4] = p0[4]; c0[5] = p0[5];
      const float* p1 = &tile[(y0 + 1) * 36 + x0];
      float4 v1 = *(const float4*)p1;
      c1[0] = v1.x; c1[1] = v1.y; c1[2] = v1.z; c1[3] = v1.w; c1[4] = p1[4]; c1[5] = p1[5];
    }
#pragma unroll
    for (int i = 0; i < 16; ++i) {
      const float* p2 = &tile[(y0 + 2 + i) * 36 + x0];
      float4 v2 = *(const float4*)p2;
      c2[0] = v2.x; c2[1] = v2.y; c2[2] = v2.z; c2[3] = v2.w; c2[4] = p2[4]; c2[5] = p2[5];
#pragma unroll
      for (int j = 0; j < 4; ++j) {
        float a = acc[i][j];
        a = fmaf(c0[j], w0, a); a = fmaf(c0[j + 1], w1, a); a = fmaf(c0[j + 2], w2, a);
        a = fmaf(c1[j], w3, a); a = fmaf(c1[j + 1], w4, a); a = fmaf(c1[j + 2], w5, a);
        a = fmaf(c2[j], w6, a); a = fmaf(c2[j + 1], w7, a); a = fmaf(c2[j + 2], w8, a);
        acc[i][j] = a;
      }
#pragma unroll
      for (int j = 0; j < 6; ++j) { c0[j] = c1[j]; c1[j] = c2[j]; }
    }
  }
  float bo = bias[o];
#pragma unroll
  for (int i = 0; i < 16; ++i)
#pragma unroll
    for (int j = 0; j < 4; ++j)
      y2[((b * 256 + o) * 32 + y0 + i) * 32 + x0 + j] = acc[i][j] + bo;
}

__global__ __launch_bounds__(256) void bn2_stats_k(const float* __restrict__ y2,
    float* __restrict__ m2, float* __restrict__ i2) {
  int o = blockIdx.x, t = threadIdx.x;
  float s = 0.f, s2 = 0.f;
  for (int i = t; i < 65536; i += 256) {
    int b = i >> 10, sp = i & 1023;
    float v = y2[((b << 8) + o) * 1024 + sp];
    s += v; s2 += v * v;
  }
  __shared__ float red[4];
  float S = block_sum(s, red, t);
  float S2 = block_sum(s2, red, t);
  if (t == 0) {
    float mu = S / 65536.f;
    m2[o] = mu;
    i2[o] = rsqrtf(S2 / 65536.f - mu * mu + EPS);
  }
}

__global__ __launch_bounds__(256) void pool2_k(const float* __restrict__ y2,
    const float* __restrict__ m2, const float* __restrict__ i2,
    const float* __restrict__ g, const float* __restrict__ bb, float* __restrict__ feat) {
  int idx = blockIdx.x * 256 + threadIdx.x;
  int d = idx & 255, s = (idx >> 8) & 255, b = idx >> 16;
  int yy = s >> 4, xx = s & 15;
  const float* base = y2 + ((size_t)(b * 256 + d) << 10);
  float mu = m2[d], iv = i2[d], gg = g[d], be = bb[d];
  float best = -1e30f;
#pragma unroll
  for (int py = 0; py < 2; ++py)
#pragma unroll
    for (int px = 0; px < 2; ++px) {
      float v = base[(2 * yy + py) * 32 + 2 * xx + px];
      v = fmaxf(gg * (v - mu) * iv + be, 0.f);
      best = fmaxf(best, v);
    }
  feat[(b * 256 + s) * 256 + d] = best;
}

// ---------------- generic tiled GEMM: C = [A|A2] @ W (+bias), 64x64 tile ------
// mode 0: direct write (+bias if z==0). mode 2: z-split partials, no bias.
__global__ __launch_bounds__(256) void gemm4x4_k(const float* __restrict__ A, int lda,
    const float* __restrict__ A2, int lda2, int K1,
    const float* __restrict__ W, const float* __restrict__ bias,
    float* __restrict__ C, int M, int N, int K, int kchunk, int mode) {
  __shared__ __align__(16) float As[16][68];
  __shared__ __align__(16) float Ws[16][68];
  int tx = threadIdx.x, ty = threadIdx.y;
  int tid = ty * 16 + tx;
  int n0 = blockIdx.x * 64, m0 = blockIdx.y * 64;
  int k_lo = blockIdx.z * kchunk;
  int k_hi = min(K, k_lo + kchunk);
  float acc[4][4];
#pragma unroll
  for (int i = 0; i < 4; ++i)
#pragma unroll
    for (int j = 0; j < 4; ++j) acc[i][j] = 0.f;
  for (int k0 = k_lo; k0 < k_hi; k0 += 16) {
    __syncthreads();
#pragma unroll
    for (int q = 0; q < 4; ++q) {
      int r = (tid >> 4) + q * 16, c = tid & 15;
      int mm = m0 + r, kk = k0 + c;
      float a = 0.f;
      if (mm < M && kk < k_hi) a = (kk < K1) ? A[(size_t)mm * lda + kk] : A2[(size_t)mm * lda2 + kk - K1];
      As[c][r] = a;
    }
#pragma unroll
    for (int q = 0; q < 4; ++q) {
      int kk = (tid >> 6) + q * 4, nn = tid & 63;
      int kg = k0 + kk, n = n0 + nn;
      Ws[kk][nn] = (kg < k_hi && n < N) ? W[(size_t)kg * N + n] : 0.f;
    }
    __syncthreads();
#pragma unroll
    for (int kk = 0; kk < 16; ++kk) {
      float4 av = *(const float4*)&As[kk][ty * 4];
      float4 wv = *(const float4*)&Ws[kk][tx * 4];
      float av4[4] = {av.x, av.y, av.z, av.w};
      float wv4[4] = {wv.x, wv.y, wv.z, wv.w};
#pragma unroll
      for (int i = 0; i < 4; ++i)
#pragma unroll
        for (int j = 0; j < 4; ++j) acc[i][j] += av4[i] * wv4[j];
    }
  }
#pragma unroll
  for (int i = 0; i < 4; ++i) {
    int mm = m0 + ty * 4 + i;
    if (mm >= M) continue;
#pragma unroll
    for (int j = 0; j < 4; ++j) {
      int n = n0 + tx * 4 + j;
      if (n >= N) continue;
      float v = acc[i][j];
      if (mode == 2) {
        C[((size_t)blockIdx.z * M + mm) * N + n] = v;
      } else {
        if (bias && blockIdx.z == 0) v += bias[n];
        C[(size_t)mm * N + n] = v;
      }
    }
  }
}

// ---------------- LayerNorm over 256-wide rows (in place) ---------------------
__global__ __launch_bounds__(256) void ln256_k(float* __restrict__ x,
    const float* __restrict__ g, const float* __restrict__ b) {
  int row = blockIdx.x, t = threadIdx.x;
  float v = x[row * 256 + t];
  __shared__ float red[4];
  float mu = block_sum(v, red, t) * (1.f / 256.f);
  float d = v - mu;
  float var = block_sum(d * d, red, t) * (1.f / 256.f);
  float rs = rsqrtf(var + EPS);
  x[row * 256 + t] = g[t] * d * rs + b[t];
}

// ---------------- attention: one block per (b,h); folds q split-K reduce ------
__global__ __launch_bounds__(256) void attn_k(const float* __restrict__ part_q,
    const float* __restrict__ qbq, const float* __restrict__ kh,
    const float* __restrict__ vh, float* __restrict__ out, int nkc) {
  int b = blockIdx.x >> 3, h = blockIdx.x & 7;
  int t = threadIdx.x;
  __shared__ float q8[256];
  __shared__ float qs[32];
  __shared__ float wgt[256];
  __shared__ float pv[256];
  __shared__ float red[4];
  {
    int d = t & 31, g = t >> 5;
    float s = 0.f;
    for (int kc = g; kc < nkc; kc += 8)
      s += part_q[(size_t)(kc * 64 + b) * 256 + h * 32 + d];
    q8[t] = s;
  }
  __syncthreads();
  if (t < 32) {
    float s = qbq[h * 32 + t];
#pragma unroll
    for (int g = 0; g < 8; ++g) s += q8[g * 32 + t];
    qs[t] = s;
  }
  __syncthreads();
  const float4* kp = (const float4*)(kh + ((size_t)((b * 256 + t) * 8 + h)) * 32);
  float sc = 0.f;
#pragma unroll
  for (int q = 0; q < 8; ++q) {
    float4 k4 = kp[q];
    sc += k4.x * qs[4 * q] + k4.y * qs[4 * q + 1] + k4.z * qs[4 * q + 2] + k4.w * qs[4 * q + 3];
  }
  sc *= 0.17677669529663687f;  // 1/sqrt(32)
  float M = block_max(sc, red, t);
  float e = __expf(sc - M);
  float S = block_sum(e, red, t);
  wgt[t] = e / S;
  __syncthreads();
  int d = t & 31, grp = t >> 5;
  float a = 0.f;
  for (int s = grp; s < 256; s += 8)
    a += wgt[s] * vh[((size_t)((b * 256 + s) * 8 + h)) * 32 + d];
  pv[t] = a;
  __syncthreads();
  if (t < 32) {
    float s = 0.f;
#pragma unroll
    for (int g2 = 0; g2 < 8; ++g2) s += pv[g2 * 32 + t];
    out[b * 256 + h * 32 + t] = s;
  }
}

// ---------------- reduce syn partials + bias + GLU + LN -> trace ring slot ----
__global__ __launch_bounds__(256) void gluln_k(const float* __restrict__ part2,
    const float* __restrict__ biasyn,
    const float* __restrict__ g, const float* __restrict__ bb,
    float* __restrict__ trace, int slot) {
  int b = blockIdx.x, t = threadIdx.x;
  float v[4];
  float s = 0.f;
#pragma unroll
  for (int i = 0; i < 4; ++i) {
    int d = i * 256 + t;
    float a = biasyn[d];
    float gg = biasyn[1024 + d];
#pragma unroll
    for (int z = 0; z < 8; ++z) {
      const float* p = part2 + (size_t)(z * 64 + b) * 2048;
      a += p[d];
      gg += p[1024 + d];
    }
    v[i] = a * sigm(gg);
    s += v[i];
  }
  __shared__ float red[4];
  float mu = block_sum(s, red, t) * (1.f / 1024.f);
  float s2 = 0.f;
#pragma unroll
  for (int i = 0; i < 4; ++i) { float d0 = v[i] - mu; s2 += d0 * d0; }
  float var = block_sum(s2, red, t) * (1.f / 1024.f);
  float rs = rsqrtf(var + EPS);
  float* tr = trace + (b * 25 + slot) * 1024;
#pragma unroll
  for (int i = 0; i < 4; ++i) {
    int d = i * 256 + t;
    tr[d] = g[d] * (v[i] - mu) * rs + bb[d];
  }
}

// ---------------- tp1 einsum + GLU: hmid[b,h,d] -------------------------------
#define FMA4(dst, sv, wv) dst.x += sv.x*wv.x; dst.y += sv.y*wv.y; dst.z += sv.z*wv.z; dst.w += sv.w*wv.w;
__global__ __launch_bounds__(256) void tp1_k(const float* __restrict__ trace,
    const float* __restrict__ w1, const float* __restrict__ b1,
    float* __restrict__ hmid, int toff) {
  int gx = blockIdx.x * 256 + threadIdx.x;  // 65536
  int d4 = gx & 255;
  int hg = (gx >> 8) & 7;
  int bp = gx >> 11;
  int b0 = bp * 2;
  int h0 = hg * 8;
  float4 acc[2][2][8];
#pragma unroll
  for (int a = 0; a < 2; ++a)
#pragma unroll
    for (int c = 0; c < 2; ++c)
#pragma unroll
      for (int u = 0; u < 8; ++u) acc[a][c][u] = make_float4(0.f, 0.f, 0.f, 0.f);
  for (int m = 0; m < 25; ++m) {
    int pm = toff + m; if (pm >= 25) pm -= 25;
    float4 t0 = *(const float4*)&trace[((b0) * 25 + pm) * 1024 + d4 * 4];
    float4 t1 = *(const float4*)&trace[((b0 + 1) * 25 + pm) * 1024 + d4 * 4];
    const float* wb = w1 + m * 131072 + d4 * 4;
#pragma unroll
    for (int u = 0; u < 8; ++u) {
      float4 wa = *(const float4*)&wb[(h0 + u) * 1024];
      float4 wg = *(const float4*)&wb[(64 + h0 + u) * 1024];
      FMA4(acc[0][0][u], t0, wa); FMA4(acc[0][1][u], t0, wg);
      FMA4(acc[1][0][u], t1, wa); FMA4(acc[1][1][u], t1, wg);
    }
  }
  int dbase = d4 * 4;
#pragma unroll
  for (int u = 0; u < 8; ++u) {
    int h = h0 + u;
#pragma unroll
    for (int bb2 = 0; bb2 < 2; ++bb2) {
      float4 av = acc[bb2][0][u], gv = acc[bb2][1][u];
      av.x += b1[(dbase + 0) * 128 + h];      av.y += b1[(dbase + 1) * 128 + h];
      av.z += b1[(dbase + 2) * 128 + h];      av.w += b1[(dbase + 3) * 128 + h];
      gv.x += b1[(dbase + 0) * 128 + 64 + h]; gv.y += b1[(dbase + 1) * 128 + 64 + h];
      gv.z += b1[(dbase + 2) * 128 + 64 + h]; gv.w += b1[(dbase + 3) * 128 + 64 + h];
      float4 hm;
      hm.x = av.x * sigm(gv.x); hm.y = av.y * sigm(gv.y);
      hm.z = av.z * sigm(gv.z); hm.w = av.w * sigm(gv.w);
      *(float4*)&hmid[((b0 + bb2) * 64 + h) * 1024 + dbase] = hm;
    }
  }
}

__global__ __launch_bounds__(256) void tp2_k(const float* __restrict__ hmid,
    const float* __restrict__ w2, const float* __restrict__ b2, float* __restrict__ act) {
  int gx = blockIdx.x * 256 + threadIdx.x;  // 65536
  int d = gx & 1023, b = gx >> 10;
  float a = b2[d * 2], gg = b2[d * 2 + 1];
  for (int h = 0; h < 64; ++h) {
    float hm = hmid[(b * 64 + h) * 1024 + d];
    a += hm * w2[(h * 2) * 1024 + d];
    gg += hm * w2[(h * 2 + 1) * 1024 + d];
  }
  act[gx] = a * sigm(gg);
}

// ---------------- synchronisation, (b,p) layout, closed-form beta -------------
__global__ __launch_bounds__(256) void synch_k(const float* __restrict__ act,
    const int* __restrict__ I, const int* __restrict__ J,
    const float* __restrict__ decay, int off, int n, int has_init,
    float* __restrict__ al, float* __restrict__ so) {
  int p = blockIdx.x * 256 + threadIdx.x;
  if (p >= SYNCH) return;
  int b = blockIdx.y;
  const float* arow = act + b * 1024 + off;
  float pp = arow[I[p]] * arow[J[p]];
  float d = decay[p];
  float r = __expf(-d);
  size_t idx = (size_t)b * SYNCH + p;
  float a = r * al[idx] + pp;
  al[idx] = a;
  float em1d = expm1f(-d);                  // r - 1  (negative)
  float em1nd = expm1f(-(float)n * d);      // r^n - 1
  float beta = (em1d == 0.f) ? (float)n : em1nd / em1d;  // (1-r^n)/(1-r)
  if (has_init) beta += em1nd + 1.f;        // + r^n
  so[idx] = a * rsqrtf(beta);
}

// ---------------- pred split-K reduce + logits + entropy certainty ------------
__global__ __launch_bounds__(256) void predent_k(const float* __restrict__ part,
    const float* __restrict__ bias, float* __restrict__ dout, int nkc, int t) {
  int b = blockIdx.x, tid = threadIdx.x;
  __shared__ float sp[1000];
  __shared__ float red[4];
  float mx = -1e30f;
  for (int i = tid; i < 1000; i += 256) {
    float s = bias[i];
    for (int kc = 0; kc < nkc; ++kc) s += part[(size_t)(kc * 64 + b) * 1000 + i];
    sp[i] = s;
    mx = fmaxf(mx, s);
  }
  float M = block_max(mx, red, tid);
  float se = 0.f;
  for (int i = tid; i < 1000; i += 256) se += __expf(sp[i] - M);
  float S = block_sum(se, red, tid);
  float lse = M + __logf(S);
  float acc = 0.f;
  for (int i = tid; i < 1000; i += 256) {
    float lp = sp[i] - lse;
    acc += __expf(lp) * lp;
    dout[b * 16000 + i * 16 + t] = sp[i];
  }
  float E = block_sum(acc, red, tid);
  if (tid == 0) {
    float ne = -E * (1.f / 6.907755278982137f);  // / ln(1000)
    dout[1024000 + b * 32 + t] = ne;
    dout[1024000 + b * 32 + 16 + t] = 1.f - ne;
  }
}

// ---------------- small setup / fold kernels ----------------------------------
__global__ void triu_k(int* __restrict__ I, int* __restrict__ J) {
  int p = blockIdx.x * 256 + threadIdx.x;
  if (p >= SYNCH) return;
  float pf = (float)p;
  int i = (int)floorf((513.f - sqrtf(513.f * 513.f - 8.f * pf)) * 0.5f);
  i = max(0, min(255, i));
  while (i > 0 && i * (513 - i) / 2 > p) --i;
  while (i < 255 && (i + 1) * (513 - (i + 1)) / 2 <= p) ++i;
  I[p] = i;
  J[p] = i + (p - i * (513 - i) / 2);
}

__global__ void initact_k(const float* sa, float* act) {
  int gx = blockIdx.x * 256 + threadIdx.x;  // 65536
  act[gx] = sa[gx & 1023];
}

__global__ void inittrace_k(const float* st, float* trace) {
  int r = blockIdx.x * 256 + threadIdx.x;  // < 25600
  int b = blockIdx.y;
  int m = r >> 10, d = r & 1023;
  trace[(b * 25 + m) * 1024 + d] = st[d * 25 + m];
}

__global__ void initsynch_k(const int* __restrict__ I, const int* __restrict__ J,
    const float* __restrict__ sa, float* aa, float* ao) {
  int p = blockIdx.x * 256 + threadIdx.x;
  if (p >= SYNCH) return;
  int b = blockIdx.y;
  size_t idx = (size_t)b * SYNCH + p;
  aa[idx] = 0.f;
  ao[idx] = sa[I[p]] * sa[J[p]];
}

__global__ void soout_k(const float* __restrict__ so, float* __restrict__ dout) {
  int p = blockIdx.x * 256 + threadIdx.x;
  if (p >= SYNCH) return;
  int b = blockIdx.y;
  dout[1026048 + (size_t)b * SYNCH + p] = so[(size_t)b * SYNCH + p];
}

// out[n] = bias2[n] + sum_k v[k] * W[k*N+n]
__global__ void vecbias_k(const float* __restrict__ v, const float* __restrict__ W,
    const float* __restrict__ bias, float* __restrict__ out, int K, int N) {
  int n = blockIdx.x * 256 + threadIdx.x;
  if (n >= N) return;
  float s = bias[n];
  for (int k = 0; k < K; ++k) s += v[k] * W[(size_t)k * N + n];
  out[n] = s;
}

__global__ void copy_k(const float* __restrict__ src, float* __restrict__ dst, int count) {
  int i = blockIdx.x * 256 + threadIdx.x;
  if (i < count) dst[i] = src[i];
}

// ------------------------------------------------------------------------------
extern "C" void kernel_launch(void* const* d_in, const int* in_sizes, int n_in,
                              void* d_out, int out_size, void* d_ws, size_t ws_size,
                              hipStream_t stream) {
  (void)in_sizes; (void)n_in; (void)out_size; (void)ws_size;
  const float* x      = (const float*)d_in[0];
  const float* c1w    = (const float*)d_in[1];
  const float* c1b    = (const float*)d_in[2];
  const float* bn1g   = (const float*)d_in[3];
  const float* bn1b   = (const float*)d_in[4];
  const float* c2w    = (const float*)d_in[5];
  const float* c2b    = (const float*)d_in[6];
  const float* bn2g   = (const float*)d_in[7];
  const float* bn2b   = (const float*)d_in[8];
  const float* kvw    = (const float*)d_in[9];
  const float* kvb    = (const float*)d_in[10];
  const float* lnkvg  = (const float*)d_in[11];
  const float* lnkvb  = (const float*)d_in[12];
  const float* qw     = (const float*)d_in[13];
  const float* qb     = (const float*)d_in[14];
  const float* wq     = (const float*)d_in[15];
  const float* bq     = (const float*)d_in[16];
  const float* wk     = (const float*)d_in[17];
  const float* bk     = (const float*)d_in[18];
  const float* wv     = (const float*)d_in[19];
  const float* bv     = (const float*)d_in[20];
  const float* wo     = (const float*)d_in[21];
  const float* bop    = (const float*)d_in[22];
  const float* synw   = (const float*)d_in[23];
  const float* synb   = (const float*)d_in[24];
  const float* lnsg   = (const float*)d_in[25];
  const float* lnsb   = (const float*)d_in[26];
  const float* t1w    = (const float*)d_in[27];
  const float* t1b    = (const float*)d_in[28];
  const float* t2w    = (const float*)d_in[29];
  const float* t2b    = (const float*)d_in[30];
  const float* outw   = (const float*)d_in[31];
  const float* outb   = (const float*)d_in[32];
  const float* sact   = (const float*)d_in[33];
  const float* strace = (const float*)d_in[34];
  const float* dca    = (const float*)d_in[35];
  const float* dco    = (const float*)d_in[36];
  float* out = (float*)d_out;

  float* W = (float*)d_ws;
  size_t off = 0;
  auto alloc = [&](size_t n) { float* p = W + off; off += (n + 63) & ~(size_t)63; return p; };
  float* h1     = alloc(16777216);   // frontend only; reused for kv/kh/vh
  float* y2     = alloc(16777216);   // frontend only; reused for qwq/wcat
  float* feat   = alloc(4194304);
  float* s1p    = alloc(16384);
  float* s2p    = alloc(16384);
  float* m1     = alloc(256); float* i1 = alloc(256);
  float* m2     = alloc(256); float* i2 = alloc(256);
  int*   tI     = (int*)alloc(32896);
  int*   tJ     = (int*)alloc(32896);
  float* aa     = alloc(2105344);
  float* ao     = alloc(2105344);
  float* sa     = alloc(2105344);
  float* so     = alloc(2105344);
  float* act    = alloc(65536);
  float* trace  = alloc(1638400);
  float* part_q = alloc(2097152);    // >= 32*64*256
  float* part2  = alloc(1048576);    // 8*64*2048
  float* hmid   = alloc(4194304);
  float* part   = alloc(8192000);    // >= 32*64*1000
  float* ath    = alloc(16384);
  float* qbq    = alloc(256);
  float* biasyn = alloc(2048);

  // aliases into dead frontend buffers
  float* kv   = h1;                  // 4194304
  float* kh   = h1 + 4194304;        // 4194304
  float* vh   = h1 + 8388608;        // 4194304
  float* qwq  = y2;                  // 32896*256 = 8421376
  float* wcat = y2 + 8421376;        // 1280*2048 = 2621440

  dim3 thr(16, 16);

  // -------- frontend --------
  conv1_stats_k<<<16384, 256, 0, stream>>>(x, c1w, c1b, s1p, s2p);
  bn_final_k<<<1, 256, 0, stream>>>(s1p, s2p, m1, i1, 262144.f);
  conv1_pool_k<<<16384, 256, 0, stream>>>(x, c1w, c1b, m1, i1, bn1g, bn1b, h1);
  conv2_k<<<1024, 256, 0, stream>>>(h1, c2w, c2b, y2);
  bn2_stats_k<<<256, 256, 0, stream>>>(y2, m2, i2);
  pool2_k<<<16384, 256, 0, stream>>>(y2, m2, i2, bn2g, bn2b, feat);
  // h1, y2 now dead -> aliases become live
  gemm4x4_k<<<dim3(4, 256, 1), thr, 0, stream>>>(feat, 256, feat, 256, 256, kvw, kvb, kv, 16384, 256, 256, 256, 0);
  ln256_k<<<16384, 256, 0, stream>>>(kv, lnkvg, lnkvb);
  gemm4x4_k<<<dim3(4, 256, 1), thr, 0, stream>>>(kv, 256, kv, 256, 256, wk, bk, kh, 16384, 256, 256, 256, 0);
  gemm4x4_k<<<dim3(4, 256, 1), thr, 0, stream>>>(kv, 256, kv, 256, 256, wv, bv, vh, 16384, 256, 256, 256, 0);
  // folded weights
  gemm4x4_k<<<dim3(4, 514, 1), thr, 0, stream>>>(qw, 256, qw, 256, 256, wq, nullptr, qwq, 32896, 256, 256, 256, 0);
  gemm4x4_k<<<dim3(32, 4, 1), thr, 0, stream>>>(wo, 256, wo, 256, 256, synw, nullptr, wcat, 256, 2048, 256, 256, 0);
  copy_k<<<8192, 256, 0, stream>>>(synw + 524288, wcat + 524288, 2097152);
  vecbias_k<<<1, 256, 0, stream>>>(qb, wq, bq, qbq, 256, 256);
  vecbias_k<<<8, 256, 0, stream>>>(bop, synw, synb, biasyn, 256, 2048);

  // -------- recurrent-state setup --------
  triu_k<<<129, 256, 0, stream>>>(tI, tJ);
  initact_k<<<256, 256, 0, stream>>>(sact, act);
  inittrace_k<<<dim3(100, 64), 256, 0, stream>>>(strace, trace);
  initsynch_k<<<dim3(129, 64), 256, 0, stream>>>(tI, tJ, sact, aa, ao);

  // -------- 16 thought iterations --------
  for (int t = 0; t < 16; ++t) {
    synch_k<<<dim3(129, 64), 256, 0, stream>>>(act, tI, tJ, dca, 768, t + 1, 0, aa, sa);
    gemm4x4_k<<<dim3(4, 1, 32), thr, 0, stream>>>(sa, 32896, sa, 32896, 32896, qwq, nullptr, part_q, 64, 256, 32896, 1028, 2);
    attn_k<<<512, 256, 0, stream>>>(part_q, qbq, kh, vh, ath, 32);
    gemm4x4_k<<<dim3(32, 1, 8), thr, 0, stream>>>(ath, 256, act, 1024, 256, wcat, nullptr, part2, 64, 2048, 1280, 160, 2);
    gluln_k<<<64, 256, 0, stream>>>(part2, biasyn, lnsg, lnsb, trace, t);
    tp1_k<<<256, 256, 0, stream>>>(trace, t1w, t1b, hmid, t + 1);
    tp2_k<<<256, 256, 0, stream>>>(hmid, t2w, t2b, act);
    synch_k<<<dim3(129, 64), 256, 0, stream>>>(act, tI, tJ, dco, 0, t + 1, 1, ao, so);
    gemm4x4_k<<<dim3(16, 1, 32), thr, 0, stream>>>(so, 32896, so, 32896, 32896, outw, nullptr, part, 64, 1000, 32896, 1028, 2);
    predent_k<<<64, 256, 0, stream>>>(part, outb, out, 32, t);
  }
  soout_k<<<dim3(129, 64), 256, 0, stream>>>(so, out);
}